// Round 2
// baseline (377.229 us; speedup 1.0000x reference)
//
#include <hip/hip_runtime.h>
#include <math.h>

// Problem: image [4,1,128,256,256] fp32 -> out [4,2,128,256,256]
//   ch0 = copy(image); ch1 = |sobel3d(image)| (separable s=[1,2,1], d=[-1,0,1])
//
// R1: software-pipelined global prefetch (plane p+1 loads issued before the
// barrier, consumed next iteration) + non-temporal output stores (via native
// vector type; HIP float4 struct is rejected by the builtin). Theory: baseline
// was latency-bound at ~18% of HBM BW because every plane iteration exposed
// full global-load latency inside a barrier-synchronized loop at 4 blocks/CU.
namespace {
constexpr int B  = 4;
constexpr int D  = 128;
constexpr int H  = 256;
constexpr int W  = 256;
constexpr int TH = 16;   // tile height
constexpr int TW = 64;   // tile width
constexpr int CH = 32;   // depth chunk per block
constexpr int AS = 68;   // sa/sb row stride (floats)
typedef float nf4 __attribute__((ext_vector_type(4)));  // native vec for nt-store
}

#define SMOOTH3(o, p0, p1, p2) \
  o.x = fmaf(2.f, p1.x, p0.x + p2.x); \
  o.y = fmaf(2.f, p1.y, p0.y + p2.y); \
  o.z = fmaf(2.f, p1.z, p0.z + p2.z); \
  o.w = fmaf(2.f, p1.w, p0.w + p2.w);
#define DIFF3(o, p0, p2) \
  o.x = p2.x - p0.x; o.y = p2.y - p0.y; o.z = p2.z - p0.z; o.w = p2.w - p0.w;

__device__ __forceinline__ void st_nt(float* p, float4 v) {
  nf4 nv; nv.x = v.x; nv.y = v.y; nv.z = v.z; nv.w = v.w;
  __builtin_nontemporal_store(nv, (nf4*)p);
}

__global__ __launch_bounds__(256, 4)
void sobel_fused(const float* __restrict__ img, float* __restrict__ out) {
  // W-pass intermediates only; double-buffered by plane parity -> 1 barrier/plane
  __shared__ float sa[2][18 * AS];   // S_W * x, rows h0-1 .. h0+16
  __shared__ float sb[2][18 * AS];   // D_W * x

  const int t  = threadIdx.x;
  const int r  = t >> 4;              // 0..15 row in tile
  const int cg = (t & 15) << 2;       // 0,4,..,60 col group
  const int w0 = blockIdx.x * TW;
  const int h0 = blockIdx.y * TH;
  const int bz = blockIdx.z;
  const int batch = bz >> 2;          // D/CH = 4 chunks per batch
  const int d0    = (bz & 3) * CH;

  const float* imgB = img + (size_t)batch * ((size_t)D * H * W);
  float* out0 = out + (size_t)batch * ((size_t)2 * D * H * W);
  float* out1 = out0 + (size_t)D * H * W;

  // row geometry (loop-invariant)
  const int  gh0    = h0 + r - 1;                       // pass-0 row (rr = r)
  const int  gh1    = h0 + r + 15;                      // pass-1 row (rr = r+16)
  const bool row0In = ((unsigned)gh0 < (unsigned)H);
  const bool pass1  = (r < 2);
  const bool row1In = pass1 && ((unsigned)gh1 < (unsigned)H);
  const bool hasM   = (w0 + cg) > 0;
  const bool hasP   = (w0 + cg + 4) < W;

  const float4 z4 = {0.f, 0.f, 0.f, 0.f};
  // per-thread 3-plane circular buffers (registers)
  float4 U0 = z4, U1 = z4, U2 = z4;   // S_H S_W
  float4 V0 = z4, V1 = z4, V2 = z4;   // S_H D_W
  float4 T0 = z4, T1 = z4, T2 = z4;   // D_H S_W

  // prefetch registers (plane for iteration jj holds input plane d0+jj-1)
  float4 px0 = z4, px1 = z4;
  float  pm0 = 0.f, pp0 = 0.f, pm1 = 0.f, pp1 = 0.f;

#define ISSUE(jj) do {                                                     \
    const int p_ = d0 + (jj) - 1;                                          \
    const bool pin_ = (p_ >= 0) && (p_ < D);                               \
    px0 = z4; pm0 = 0.f; pp0 = 0.f;                                        \
    px1 = z4; pm1 = 0.f; pp1 = 0.f;                                        \
    if (pin_ && row0In) {                                                  \
      const float* rp = imgB + ((size_t)p_ * H + gh0) * W + (w0 + cg);     \
      px0 = *(const float4*)rp;                                            \
      if (hasM) pm0 = rp[-1];                                              \
      if (hasP) pp0 = rp[4];                                               \
    }                                                                      \
    if (pin_ && row1In) {                                                  \
      const float* rp = imgB + ((size_t)p_ * H + gh1) * W + (w0 + cg);     \
      px1 = *(const float4*)rp;                                            \
      if (hasM) pm1 = rp[-1];                                              \
      if (hasP) pp1 = rp[4];                                               \
    }                                                                      \
  } while (0)

  // prologue: prefetch for j=0 (plane d0-1)
  ISSUE(0);

  for (int j = 0; j <= CH + 1; ++j) {
    const int p   = d0 + j - 1;               // input plane consumed this iter
    const bool cpin = (p >= 0) && (p < D);
    const bool wr0  = (j >= 1) && (j <= CH);  // p is an output plane of chunk
    const int buf = j & 1;

    // ---- Phase A: W-pass from prefetched registers ----
    {
      float4 av, bv;
      av.x = fmaf(2.f, px0.x, pm0   + px0.y);
      av.y = fmaf(2.f, px0.y, px0.x + px0.z);
      av.z = fmaf(2.f, px0.z, px0.y + px0.w);
      av.w = fmaf(2.f, px0.w, px0.z + pp0);
      bv.x = px0.y - pm0; bv.y = px0.z - px0.x;
      bv.z = px0.w - px0.y; bv.w = pp0 - px0.z;
      *(float4*)&sa[buf][r * AS + cg] = av;
      *(float4*)&sb[buf][r * AS + cg] = bv;
      // fused channel-0 copy: rows h0..h0+14 come from pass-0 rows rr=1..15
      if (wr0 && cpin && row0In && r >= 1)
        st_nt(&out0[((size_t)p * H + gh0) * W + (w0 + cg)], px0);
    }
    if (pass1) {
      float4 av, bv;
      av.x = fmaf(2.f, px1.x, pm1   + px1.y);
      av.y = fmaf(2.f, px1.y, px1.x + px1.z);
      av.z = fmaf(2.f, px1.z, px1.y + px1.w);
      av.w = fmaf(2.f, px1.w, px1.z + pp1);
      bv.x = px1.y - pm1; bv.y = px1.z - px1.x;
      bv.z = px1.w - px1.y; bv.w = pp1 - px1.z;
      *(float4*)&sa[buf][(r + 16) * AS + cg] = av;
      *(float4*)&sb[buf][(r + 16) * AS + cg] = bv;
      // rr=16 (r==0) covers row h0+15; always in range (h0 <= H-TH)
      if (wr0 && cpin && r == 0)
        st_nt(&out0[((size_t)p * H + gh1) * W + (w0 + cg)], px1);
    }

    // ---- issue next plane's loads; latency hides under barrier+B+C ----
    if (j <= CH) ISSUE(j + 1);

    __syncthreads();

    // ---- Phase B: H-pass -> register circular buffers ----
    float4 a0 = *(const float4*)&sa[buf][(r    ) * AS + cg];
    float4 a1 = *(const float4*)&sa[buf][(r + 1) * AS + cg];
    float4 a2 = *(const float4*)&sa[buf][(r + 2) * AS + cg];
    float4 b0 = *(const float4*)&sb[buf][(r    ) * AS + cg];
    float4 b1 = *(const float4*)&sb[buf][(r + 1) * AS + cg];
    float4 b2 = *(const float4*)&sb[buf][(r + 2) * AS + cg];
    float4 Un, Vn, Tn;
    SMOOTH3(Un, a0, a1, a2);
    DIFF3(Tn, a0, a2);
    SMOOTH3(Vn, b0, b1, b2);
    U0 = U1; U1 = U2; U2 = Un;
    V0 = V1; V1 = V2; V2 = Vn;
    T0 = T1; T1 = T2; T2 = Tn;

    // ---- Phase C: D-combination + magnitude (pure registers) ----
    if (j >= 2) {
      const int dout = d0 + j - 2;
      float4 gx, gy, gz, m;
      SMOOTH3(gx, V0, V1, V2);   // Gx = S_D (S_H D_W)
      SMOOTH3(gy, T0, T1, T2);   // Gy = S_D (D_H S_W)
      DIFF3(gz, U0, U2);         // Gz = D_D (S_H S_W)
      m.x = sqrtf(fmaf(gx.x, gx.x, fmaf(gy.x, gy.x, fmaf(gz.x, gz.x, 1e-8f))));
      m.y = sqrtf(fmaf(gx.y, gx.y, fmaf(gy.y, gy.y, fmaf(gz.y, gz.y, 1e-8f))));
      m.z = sqrtf(fmaf(gx.z, gx.z, fmaf(gy.z, gy.z, fmaf(gz.z, gz.z, 1e-8f))));
      m.w = sqrtf(fmaf(gx.w, gx.w, fmaf(gy.w, gy.w, fmaf(gz.w, gz.w, 1e-8f))));
      st_nt(&out1[((size_t)dout * H + (h0 + r)) * W + (w0 + cg)], m);
    }
  }
#undef ISSUE
}

extern "C" void kernel_launch(void* const* d_in, const int* in_sizes, int n_in,
                              void* d_out, int out_size, void* d_ws, size_t ws_size,
                              hipStream_t stream) {
  const float* img = (const float*)d_in[0];
  float* out = (float*)d_out;
  dim3 grid(W / TW, H / TH, B * (D / CH));   // (4, 16, 16) = 1024 blocks
  sobel_fused<<<grid, dim3(256), 0, stream>>>(img, out);
}